// Round 1
// baseline (314.750 us; speedup 1.0000x reference)
//
#include <hip/hip_runtime.h>
#include <stdint.h>

// ---------------------------------------------------------------------------
// Attention_24206435680257 : SAM-style attention, B=8 N=1088 C=768 nh=12 hd=64
// Pipeline (all bf16 MFMA, fp32 accum):
//   1. cvt x, qkv_w, proj_w -> bf16
//   2. GEMM qkv = x @ qkv_w^T + b  -> scatter q,k,v [96][1088][64] bf16
//   3. transpose v -> vT [96][64][1088]
//   4. relpos: relh/relw [96][1024][32] fp32
//   5. flash attention (64-key chunks, online softmax, bias, mask>=1056)
//   6. GEMM out = attn @ proj_w^T + proj_b -> fp32 d_out
// ws layout (bytes):
//   xbf/attnbf 0..13369344 | wqkv ..16908288 | wproj ..18087936
//   qbf ..31457280 | kbf ..44826624 | vbf ..58195968 | vtbf ..71565312
//   relh ..84148224 | relw ..96731136
// ---------------------------------------------------------------------------

typedef __attribute__((ext_vector_type(8))) short bf16x8;
typedef __attribute__((ext_vector_type(4))) float f32x4;

#define DEVINL static __device__ __forceinline__

DEVINL unsigned short f2bf(float f) {
  unsigned u = __builtin_bit_cast(unsigned, f);
  u += 0x7FFFu + ((u >> 16) & 1u);
  return (unsigned short)(u >> 16);
}
DEVINL float bf2f(unsigned short h) {
  unsigned u = ((unsigned)h) << 16;
  return __builtin_bit_cast(float, u);
}
DEVINL void gload_lds16(const void* g, void* l) {
  __builtin_amdgcn_global_load_lds(
      (const __attribute__((address_space(1))) unsigned int*)g,
      (__attribute__((address_space(3))) unsigned int*)l, 16, 0, 0);
}

// ------------------------------- f32 -> bf16 -------------------------------
__global__ void k_cvt(const float* __restrict__ in, unsigned short* __restrict__ out, int n4) {
  int i = blockIdx.x * 256 + threadIdx.x;
  int stride = gridDim.x * 256;
  for (; i < n4; i += stride) {
    float4 v = ((const float4*)in)[i];
    ushort4 o = make_ushort4(f2bf(v.x), f2bf(v.y), f2bf(v.z), f2bf(v.w));
    ((ushort4*)out)[i] = o;
  }
}

// ------------------------- bt-GEMM: C = A @ Bm^T ---------------------------
// A [M][K] bf16, Bm [N][K] bf16. 128x128 tile, BK=64, 4 waves (2x2), each
// wave 64x64 via 4x4 frags of 16x16x32 MFMA. XOR-swizzled LDS (8 slots of
// 16B per 128B row), staged with global_load_lds from pre-swizzled source.
// EPI 0: qkv scatter (bf16 q/k/v + qkv_b). EPI 1: fp32 C + bias.
template <int EPI>
__global__ __launch_bounds__(256) void k_gemm_bt(
    const unsigned short* __restrict__ A, const unsigned short* __restrict__ Bm,
    const float* __restrict__ bias, float* __restrict__ Cf,
    unsigned short* __restrict__ oq, unsigned short* __restrict__ ok,
    unsigned short* __restrict__ ov, int M, int N, int K) {
  __shared__ __align__(16) unsigned short lA[128 * 64];
  __shared__ __align__(16) unsigned short lB[128 * 64];
  const int t = threadIdx.x;
  const int w = t >> 6, l = t & 63;
  const int wm = w >> 1, wn = w & 1;
  const int g = l >> 4, li = l & 15;
  const int row0 = blockIdx.x * 128, col0 = blockIdx.y * 128;
  const unsigned short* Ab = A + (size_t)row0 * K;
  const unsigned short* Bb = Bm + (size_t)col0 * K;
  const f32x4 zero = {0.f, 0.f, 0.f, 0.f};
  f32x4 acc[4][4];
#pragma unroll
  for (int i = 0; i < 4; ++i)
#pragma unroll
    for (int j = 0; j < 4; ++j) acc[i][j] = zero;

  const int srow = t >> 3;                      // + p*32 per pass
  const int scs = (t & 7) ^ (srow & 7);         // pre-swizzled source slot

  for (int kt = 0; kt < K; kt += 64) {
#pragma unroll
    for (int p = 0; p < 4; ++p) {
      int r = p * 32 + srow;
      gload_lds16(Ab + (size_t)r * K + kt + scs * 8, lA + p * 2048 + w * 512);
      gload_lds16(Bb + (size_t)r * K + kt + scs * 8, lB + p * 2048 + w * 512);
    }
    __syncthreads();
#pragma unroll
    for (int kh = 0; kh < 2; ++kh) {
      bf16x8 af[4], bfv[4];
#pragma unroll
      for (int mf = 0; mf < 4; ++mf) {
        int r = wm * 64 + mf * 16 + li;
        int c8 = (kh * 4 + g) ^ (r & 7);
        af[mf] = *(const bf16x8*)(lA + r * 64 + c8 * 8);
      }
#pragma unroll
      for (int nf = 0; nf < 4; ++nf) {
        int r = wn * 64 + nf * 16 + li;
        int c8 = (kh * 4 + g) ^ (r & 7);
        bfv[nf] = *(const bf16x8*)(lB + r * 64 + c8 * 8);
      }
#pragma unroll
      for (int mf = 0; mf < 4; ++mf)
#pragma unroll
        for (int nf = 0; nf < 4; ++nf)
          acc[mf][nf] = __builtin_amdgcn_mfma_f32_16x16x32_bf16(af[mf], bfv[nf], acc[mf][nf], 0, 0, 0);
    }
    __syncthreads();
  }

#pragma unroll
  for (int mf = 0; mf < 4; ++mf) {
#pragma unroll
    for (int nf = 0; nf < 4; ++nf) {
      const int jc = col0 + wn * 64 + nf * 16 + li;
      const float bj = bias[jc];
#pragma unroll
      for (int rg = 0; rg < 4; ++rg) {
        const int m = row0 + wm * 64 + mf * 16 + g * 4 + rg;
        float val = acc[mf][nf][rg] + bj;
        if (EPI == 0) {
          int which = jc / 768;
          int jr = jc - which * 768;
          int head = jr >> 6, d = jr & 63;
          int b = m / 1088;
          int n = m - b * 1088;
          size_t idx = (((size_t)(b * 12 + head)) * 1088 + n) * 64 + d;
          unsigned short bv = f2bf(val);
          if (which == 0) oq[idx] = bv;
          else if (which == 1) ok[idx] = bv;
          else ov[idx] = bv;
        } else {
          Cf[(size_t)m * N + jc] = val;
        }
      }
    }
  }
}

// ------------------------- v [96][1088][64] -> vT [96][64][1088] -----------
__global__ __launch_bounds__(256) void k_vt(const unsigned short* __restrict__ v,
                                            unsigned short* __restrict__ vt) {
  __shared__ unsigned short tile[64 * 66];  // pad 66: 2-way max on column gathers
  const int bh = blockIdx.y, nt = blockIdx.x, t = threadIdx.x;
  const unsigned short* src = v + (((size_t)bh * 1088) + nt * 64) * 64;
#pragma unroll
  for (int i = 0; i < 2; ++i) {
    int c = t + 256 * i;
    int r = c >> 3, d8 = (c & 7) * 8;
    uint4 val = *(const uint4*)(src + (size_t)r * 64 + d8);
    const unsigned short* s8 = (const unsigned short*)&val;
#pragma unroll
    for (int j = 0; j < 8; ++j) tile[r * 66 + d8 + j] = s8[j];
  }
  __syncthreads();
  unsigned short* dst = vt + ((size_t)bh * 64) * 1088 + nt * 64;
#pragma unroll
  for (int i = 0; i < 2; ++i) {
    int c = t + 256 * i;
    int d = c >> 3, n8 = (c & 7) * 8;
    unsigned short tmp[8];
#pragma unroll
    for (int j = 0; j < 8; ++j) tmp[j] = tile[(n8 + j) * 66 + d];
    *(uint4*)(dst + (size_t)d * 1088 + n8) = *(const uint4*)tmp;
  }
}

// -------- relh[bh][q][kh] = sum_d q[bh][q][d]*rel_pos_h[qh-kh+31][d] -------
__global__ __launch_bounds__(256) void k_relpos(const unsigned short* __restrict__ qbf,
                                                const float* __restrict__ rph,
                                                const float* __restrict__ rpw,
                                                float* __restrict__ relh,
                                                float* __restrict__ relw) {
  __shared__ __align__(16) unsigned short qlds[32 * 64];
  __shared__ float rh[32 * 65];
  __shared__ float rw[63 * 65];
  const int bh = blockIdx.y, qh = blockIdx.x, t = threadIdx.x;
  {
    int qw = t >> 3, d8 = (t & 7) * 8;
    *(uint4*)(qlds + qw * 64 + d8) =
        *(const uint4*)(qbf + (((size_t)bh * 1088) + qh * 32 + qw) * 64 + d8);
  }
  for (int idx = t; idx < 32 * 64; idx += 256) {
    int r = idx >> 6, d = idx & 63;
    rh[r * 65 + d] = rph[(size_t)(qh + 31 - r) * 64 + d];
  }
  for (int idx = t; idx < 63 * 64; idx += 256) {
    int r = idx >> 6, d = idx & 63;
    rw[r * 65 + d] = rpw[(size_t)r * 64 + d];
  }
  __syncthreads();
  const int kx = t & 31;
#pragma unroll
  for (int i = 0; i < 4; ++i) {
    int qw = (t >> 5) + 8 * i;
    const unsigned short* qrow = qlds + qw * 64;
    const float* rhrow = rh + kx * 65;
    const float* rwrow = rw + (qw - kx + 31) * 65;
    float sh = 0.f, sw = 0.f;
    for (int d = 0; d < 64; ++d) {
      float qv = bf2f(qrow[d]);
      sh += qv * rhrow[d];
      sw += qv * rwrow[d];
    }
    size_t base = (((size_t)bh * 1024) + qh * 32 + qw) * 32 + kx;
    relh[base] = sh;
    relw[base] = sw;
  }
}

// ------------------------------ flash attention ----------------------------
// grid (17 qtiles, 96 bh), 4 waves: wave w owns q rows [qt*64+w*16, +16).
// Chunks of 64 keys; S = (q.k)*0.125 + bias; keys >= 1056 masked; online
// softmax (16-lane-group shfl reduce); P via per-wave swizzled LDS -> PV MFMA.
__global__ __launch_bounds__(256) void k_flash(
    const unsigned short* __restrict__ qbf, const unsigned short* __restrict__ kbf,
    const unsigned short* __restrict__ vtbf, const float* __restrict__ relh,
    const float* __restrict__ relw, unsigned short* __restrict__ attnbf) {
  __shared__ __align__(16) unsigned short lK[64 * 64];
  __shared__ __align__(16) unsigned short lV[64 * 64];  // vT tile [d][k]
  __shared__ float lrh[64 * 32];
  __shared__ float lrw[64 * 32];
  __shared__ __align__(16) unsigned short lP[4 * 16 * 64];
  const int bh = blockIdx.y, qt = blockIdx.x, t = threadIdx.x;
  const int w = t >> 6, l = t & 63;
  const int g = l >> 4, li = l & 15;
  const bool hasbias = (qt < 16);
  if (hasbias) {
#pragma unroll
    for (int i = 0; i < 2; ++i) {
      int idx = t + 256 * i;
      int r = idx >> 3, c4 = (idx & 7) * 4;
      *(float4*)(lrh + r * 32 + c4) =
          *(const float4*)(relh + (((size_t)bh * 1024) + qt * 64 + r) * 32 + c4);
      *(float4*)(lrw + r * 32 + c4) =
          *(const float4*)(relw + (((size_t)bh * 1024) + qt * 64 + r) * 32 + c4);
    }
  }
  bf16x8 qf0, qf1;
  {
    const int qabs = qt * 64 + w * 16 + li;
    const unsigned short* qp = qbf + (((size_t)bh * 1088) + qabs) * 64 + g * 8;
    qf0 = *(const bf16x8*)(qp);
    qf1 = *(const bf16x8*)(qp + 32);
  }
  const f32x4 zero = {0.f, 0.f, 0.f, 0.f};
  f32x4 oacc[4];
#pragma unroll
  for (int i = 0; i < 4; ++i) oacc[i] = zero;
  float mrun[4] = {-1e30f, -1e30f, -1e30f, -1e30f};
  float lrun[4] = {0.f, 0.f, 0.f, 0.f};
  const unsigned short* Kb = kbf + (size_t)bh * 1088 * 64;
  const unsigned short* Vb = vtbf + (size_t)bh * 64 * 1088;
  const int srow = t >> 3;
  const int scs = (t & 7) ^ (srow & 7);
  unsigned short* myP = lP + w * 1024;

  for (int kc = 0; kc < 17; ++kc) {
#pragma unroll
    for (int p = 0; p < 2; ++p) {
      int r = p * 32 + srow;
      gload_lds16(Kb + ((size_t)(kc * 64 + r)) * 64 + scs * 8, lK + p * 2048 + w * 512);
      gload_lds16(Vb + (size_t)r * 1088 + kc * 64 + scs * 8, lV + p * 2048 + w * 512);
    }
    __syncthreads();
    f32x4 sacc[4];
#pragma unroll
    for (int i = 0; i < 4; ++i) sacc[i] = zero;
#pragma unroll
    for (int nf = 0; nf < 4; ++nf) {
      int r = nf * 16 + li;
      int c8a = (0 * 4 + g) ^ (r & 7);
      int c8b = (1 * 4 + g) ^ (r & 7);
      bf16x8 kfa = *(const bf16x8*)(lK + r * 64 + c8a * 8);
      bf16x8 kfb = *(const bf16x8*)(lK + r * 64 + c8b * 8);
      sacc[nf] = __builtin_amdgcn_mfma_f32_16x16x32_bf16(qf0, kfa, sacc[nf], 0, 0, 0);
      sacc[nf] = __builtin_amdgcn_mfma_f32_16x16x32_bf16(qf1, kfb, sacc[nf], 0, 0, 0);
    }
    float sv[4][4];
#pragma unroll
    for (int nf = 0; nf < 4; ++nf) {
      const int kb = kc * 64 + nf * 16;
      const int kh = kb >> 5;
      const int kwb = kb & 31;
#pragma unroll
      for (int r = 0; r < 4; ++r) {
        float x = sacc[nf][r] * 0.125f;
        if (hasbias && kc < 16) {
          int qr = w * 16 + g * 4 + r;
          x += lrh[qr * 32 + kh] + lrw[qr * 32 + kwb + li];
        }
        if (kc == 16 && (kb + li) >= 1056) x = -1e30f;
        sv[nf][r] = x;
      }
    }
    float alpha[4];
#pragma unroll
    for (int r = 0; r < 4; ++r) {
      float m0 = fmaxf(fmaxf(sv[0][r], sv[1][r]), fmaxf(sv[2][r], sv[3][r]));
      m0 = fmaxf(m0, __shfl_xor(m0, 1));
      m0 = fmaxf(m0, __shfl_xor(m0, 2));
      m0 = fmaxf(m0, __shfl_xor(m0, 4));
      m0 = fmaxf(m0, __shfl_xor(m0, 8));
      float mn = fmaxf(mrun[r], m0);
      alpha[r] = __expf(mrun[r] - mn);
      mrun[r] = mn;
    }
    float rsum[4] = {0.f, 0.f, 0.f, 0.f};
    float pv[4][4];
#pragma unroll
    for (int nf = 0; nf < 4; ++nf)
#pragma unroll
      for (int r = 0; r < 4; ++r) {
        float p = __expf(sv[nf][r] - mrun[r]);
        pv[nf][r] = p;
        rsum[r] += p;
      }
#pragma unroll
    for (int r = 0; r < 4; ++r) {
      rsum[r] += __shfl_xor(rsum[r], 1);
      rsum[r] += __shfl_xor(rsum[r], 2);
      rsum[r] += __shfl_xor(rsum[r], 4);
      rsum[r] += __shfl_xor(rsum[r], 8);
      lrun[r] = lrun[r] * alpha[r] + rsum[r];
    }
    // P -> per-wave swizzled LDS (write: row=g*4+r, col bytes nf*32+li*2)
#pragma unroll
    for (int nf = 0; nf < 4; ++nf)
#pragma unroll
      for (int r = 0; r < 4; ++r) {
        int row = g * 4 + r;
        int cb = nf * 32 + li * 2;
        int ab = row * 128 + (cb ^ ((row & 7) << 4));
        *(unsigned short*)((char*)myP + ab) = f2bf(pv[nf][r]);
      }
#pragma unroll
    for (int df = 0; df < 4; ++df) {
      oacc[df][0] *= alpha[0];
      oacc[df][1] *= alpha[1];
      oacc[df][2] *= alpha[2];
      oacc[df][3] *= alpha[3];
    }
#pragma unroll
    for (int kh2 = 0; kh2 < 2; ++kh2) {
      int ab = li * 128 + ((kh2 * 64 + g * 16) ^ ((li & 7) << 4));
      bf16x8 pf = *(const bf16x8*)((const char*)myP + ab);
#pragma unroll
      for (int df = 0; df < 4; ++df) {
        int r = df * 16 + li;
        int c8 = (kh2 * 4 + g) ^ (r & 7);
        bf16x8 vf = *(const bf16x8*)(lV + r * 64 + c8 * 8);
        oacc[df] = __builtin_amdgcn_mfma_f32_16x16x32_bf16(pf, vf, oacc[df], 0, 0, 0);
      }
    }
    __syncthreads();
  }
  const int b = bh / 12, head = bh - (bh / 12) * 12;
  float inv[4];
#pragma unroll
  for (int r = 0; r < 4; ++r) inv[r] = 1.f / lrun[r];
#pragma unroll
  for (int df = 0; df < 4; ++df)
#pragma unroll
    for (int r = 0; r < 4; ++r) {
      int n = qt * 64 + w * 16 + g * 4 + r;
      int col = head * 64 + df * 16 + li;
      attnbf[(((size_t)b * 1088) + n) * 768 + col] = f2bf(oacc[df][r] * inv[r]);
    }
}

// ---------------------------------------------------------------------------
extern "C" void kernel_launch(void* const* d_in, const int* in_sizes, int n_in,
                              void* d_out, int out_size, void* d_ws, size_t ws_size,
                              hipStream_t stream) {
  const float* x = (const float*)d_in[0];
  const float* qkv_w = (const float*)d_in[1];
  const float* qkv_b = (const float*)d_in[2];
  const float* proj_w = (const float*)d_in[3];
  const float* proj_b = (const float*)d_in[4];
  const float* rph = (const float*)d_in[5];
  const float* rpw = (const float*)d_in[6];
  float* out = (float*)d_out;

  char* ws = (char*)d_ws;
  unsigned short* xbf = (unsigned short*)(ws + 0);
  unsigned short* attnbf = xbf;  // alias: xbf dead after qkv GEMM
  unsigned short* wqkv = (unsigned short*)(ws + 13369344);
  unsigned short* wproj = (unsigned short*)(ws + 16908288);
  unsigned short* qbf = (unsigned short*)(ws + 18087936);
  unsigned short* kbf = (unsigned short*)(ws + 31457280);
  unsigned short* vbf = (unsigned short*)(ws + 44826624);
  unsigned short* vtbf = (unsigned short*)(ws + 58195968);
  float* relh = (float*)(ws + 71565312);
  float* relw = (float*)(ws + 84148224);

  k_cvt<<<dim3(1024), dim3(256), 0, stream>>>(x, xbf, 8704 * 768 / 4);
  k_cvt<<<dim3(512), dim3(256), 0, stream>>>(qkv_w, wqkv, 2304 * 768 / 4);
  k_cvt<<<dim3(128), dim3(256), 0, stream>>>(proj_w, wproj, 768 * 768 / 4);
  k_gemm_bt<0><<<dim3(68, 18), dim3(256), 0, stream>>>(xbf, wqkv, qkv_b, nullptr,
                                                       qbf, kbf, vbf, 8704, 2304, 768);
  k_vt<<<dim3(17, 96), dim3(256), 0, stream>>>(vbf, vtbf);
  k_relpos<<<dim3(32, 96), dim3(256), 0, stream>>>(qbf, rph, rpw, relh, relw);
  k_flash<<<dim3(17, 96), dim3(256), 0, stream>>>(qbf, kbf, vtbf, relh, relw, attnbf);
  k_gemm_bt<1><<<dim3(68, 6), dim3(256), 0, stream>>>(attnbf, wproj, proj_b, out,
                                                      nullptr, nullptr, nullptr, 8704, 768, 768);
}

// Round 2
// 260.763 us; speedup vs baseline: 1.2070x; 1.2070x over previous
//
#include <hip/hip_runtime.h>
#include <stdint.h>

// ---------------------------------------------------------------------------
// Attention_24206435680257 : SAM-style attention, B=8 N=1088 C=768 nh=12 hd=64
//   1. cvt x, qkv_w, proj_w -> bf16
//   2. GEMM qkv = x @ qkv_w^T + b -> scatter q,k,v [96][1088][64] bf16
//      (q pre-scaled by 0.125*log2e so flash softmax runs in exp2 domain)
//   3. transpose v -> vT [96][64][1088]
//   4. relpos: relh/relw [96][1024][32] fp32 (x8 to recover log2e*bias)
//   5. flash attention v2: swapped-operand 32x32 MFMA, in-register softmax
//   6. GEMM out = attn @ proj_w^T + proj_b -> fp32 d_out
// ---------------------------------------------------------------------------

typedef __attribute__((ext_vector_type(8))) short bf16x8;
typedef __attribute__((ext_vector_type(4))) float f32x4;
typedef __attribute__((ext_vector_type(16))) float f32x16;
typedef __attribute__((ext_vector_type(2))) int i32x2;
typedef __attribute__((ext_vector_type(4))) int i32x4;

#define DEVINL static __device__ __forceinline__

DEVINL unsigned short f2bf(float f) {
  unsigned u = __builtin_bit_cast(unsigned, f);
  u += 0x7FFFu + ((u >> 16) & 1u);
  return (unsigned short)(u >> 16);
}
DEVINL float bf2f(unsigned short h) {
  unsigned u = ((unsigned)h) << 16;
  return __builtin_bit_cast(float, u);
}
DEVINL void gload_lds16(const void* g, void* l) {
  __builtin_amdgcn_global_load_lds(
      (const __attribute__((address_space(1))) unsigned int*)g,
      (__attribute__((address_space(3))) unsigned int*)l, 16, 0, 0);
}
DEVINL float exp2_hw(float x) {
  float r;
  asm("v_exp_f32 %0, %1" : "=v"(r) : "v"(x));
  return r;
}
DEVINL unsigned cvtpk_bf16(float lo, float hi) {
  unsigned r;
  asm("v_cvt_pk_bf16_f32 %0, %1, %2" : "=v"(r) : "v"(lo), "v"(hi));
  return r;
}

// ------------------------------- f32 -> bf16 -------------------------------
__global__ void k_cvt(const float* __restrict__ in, unsigned short* __restrict__ out, int n4) {
  int i = blockIdx.x * 256 + threadIdx.x;
  int stride = gridDim.x * 256;
  for (; i < n4; i += stride) {
    float4 v = ((const float4*)in)[i];
    ushort4 o = make_ushort4(f2bf(v.x), f2bf(v.y), f2bf(v.z), f2bf(v.w));
    ((ushort4*)out)[i] = o;
  }
}

// ------------------------- bt-GEMM: C = A @ Bm^T ---------------------------
template <int EPI>
__global__ __launch_bounds__(256) void k_gemm_bt(
    const unsigned short* __restrict__ A, const unsigned short* __restrict__ Bm,
    const float* __restrict__ bias, float* __restrict__ Cf,
    unsigned short* __restrict__ oq, unsigned short* __restrict__ ok,
    unsigned short* __restrict__ ov, int M, int N, int K) {
  __shared__ __align__(16) unsigned short lA[128 * 64];
  __shared__ __align__(16) unsigned short lB[128 * 64];
  const int t = threadIdx.x;
  const int w = t >> 6, l = t & 63;
  const int wm = w >> 1, wn = w & 1;
  const int g = l >> 4, li = l & 15;
  const int row0 = blockIdx.x * 128, col0 = blockIdx.y * 128;
  const unsigned short* Ab = A + (size_t)row0 * K;
  const unsigned short* Bb = Bm + (size_t)col0 * K;
  const f32x4 zero = {0.f, 0.f, 0.f, 0.f};
  f32x4 acc[4][4];
#pragma unroll
  for (int i = 0; i < 4; ++i)
#pragma unroll
    for (int j = 0; j < 4; ++j) acc[i][j] = zero;

  const int srow = t >> 3;
  const int scs = (t & 7) ^ (srow & 7);

  for (int kt = 0; kt < K; kt += 64) {
#pragma unroll
    for (int p = 0; p < 4; ++p) {
      int r = p * 32 + srow;
      gload_lds16(Ab + (size_t)r * K + kt + scs * 8, lA + p * 2048 + w * 512);
      gload_lds16(Bb + (size_t)r * K + kt + scs * 8, lB + p * 2048 + w * 512);
    }
    __syncthreads();
#pragma unroll
    for (int kh = 0; kh < 2; ++kh) {
      bf16x8 af[4], bfv[4];
#pragma unroll
      for (int mf = 0; mf < 4; ++mf) {
        int r = wm * 64 + mf * 16 + li;
        int c8 = (kh * 4 + g) ^ (r & 7);
        af[mf] = *(const bf16x8*)(lA + r * 64 + c8 * 8);
      }
#pragma unroll
      for (int nf = 0; nf < 4; ++nf) {
        int r = wn * 64 + nf * 16 + li;
        int c8 = (kh * 4 + g) ^ (r & 7);
        bfv[nf] = *(const bf16x8*)(lB + r * 64 + c8 * 8);
      }
#pragma unroll
      for (int mf = 0; mf < 4; ++mf)
#pragma unroll
        for (int nf = 0; nf < 4; ++nf)
          acc[mf][nf] = __builtin_amdgcn_mfma_f32_16x16x32_bf16(af[mf], bfv[nf], acc[mf][nf], 0, 0, 0);
    }
    __syncthreads();
  }

#pragma unroll
  for (int mf = 0; mf < 4; ++mf) {
#pragma unroll
    for (int nf = 0; nf < 4; ++nf) {
      const int jc = col0 + wn * 64 + nf * 16 + li;
      const float bj = bias[jc];
#pragma unroll
      for (int rg = 0; rg < 4; ++rg) {
        const int m = row0 + wm * 64 + mf * 16 + g * 4 + rg;
        float val = acc[mf][nf][rg] + bj;
        if (EPI == 0) {
          int which = jc / 768;
          int jr = jc - which * 768;
          int head = jr >> 6, d = jr & 63;
          int b = m / 1088;
          int n = m - b * 1088;
          size_t idx = (((size_t)(b * 12 + head)) * 1088 + n) * 64 + d;
          if (which == 0) val *= 0.18033688011112042f;  // 0.125 * log2(e)
          unsigned short bv = f2bf(val);
          if (which == 0) oq[idx] = bv;
          else if (which == 1) ok[idx] = bv;
          else ov[idx] = bv;
        } else {
          Cf[(size_t)m * N + jc] = val;
        }
      }
    }
  }
}

// ------------------------- v [96][1088][64] -> vT [96][64][1088] -----------
__global__ __launch_bounds__(256) void k_vt(const unsigned short* __restrict__ v,
                                            unsigned short* __restrict__ vt) {
  __shared__ unsigned short tile[64 * 66];
  const int bh = blockIdx.y, nt = blockIdx.x, t = threadIdx.x;
  const unsigned short* src = v + (((size_t)bh * 1088) + nt * 64) * 64;
#pragma unroll
  for (int i = 0; i < 2; ++i) {
    int c = t + 256 * i;
    int r = c >> 3, d8 = (c & 7) * 8;
    uint4 val = *(const uint4*)(src + (size_t)r * 64 + d8);
    const unsigned short* s8 = (const unsigned short*)&val;
#pragma unroll
    for (int j = 0; j < 8; ++j) tile[r * 66 + d8 + j] = s8[j];
  }
  __syncthreads();
  unsigned short* dst = vt + ((size_t)bh * 64) * 1088 + nt * 64;
#pragma unroll
  for (int i = 0; i < 2; ++i) {
    int c = t + 256 * i;
    int d = c >> 3, n8 = (c & 7) * 8;
    unsigned short tmp[8];
#pragma unroll
    for (int j = 0; j < 8; ++j) tmp[j] = tile[(n8 + j) * 66 + d];
    *(uint4*)(dst + (size_t)d * 1088 + n8) = *(const uint4*)tmp;
  }
}

// ---- relh[bh][q][kh] = 8 * sum_d qscaled[bh][q][d]*rel_pos_h[qh-kh+31][d] --
__global__ __launch_bounds__(256) void k_relpos(const unsigned short* __restrict__ qbf,
                                                const float* __restrict__ rph,
                                                const float* __restrict__ rpw,
                                                float* __restrict__ relh,
                                                float* __restrict__ relw) {
  __shared__ __align__(16) unsigned short qlds[32 * 64];
  __shared__ float rh[32 * 65];
  __shared__ float rw[63 * 65];
  const int bh = blockIdx.y, qh = blockIdx.x, t = threadIdx.x;
  {
    int qw = t >> 3, d8 = (t & 7) * 8;
    *(uint4*)(qlds + qw * 64 + d8) =
        *(const uint4*)(qbf + (((size_t)bh * 1088) + qh * 32 + qw) * 64 + d8);
  }
  for (int idx = t; idx < 32 * 64; idx += 256) {
    int r = idx >> 6, d = idx & 63;
    rh[r * 65 + d] = rph[(size_t)(qh + 31 - r) * 64 + d];
  }
  for (int idx = t; idx < 63 * 64; idx += 256) {
    int r = idx >> 6, d = idx & 63;
    rw[r * 65 + d] = rpw[(size_t)r * 64 + d];
  }
  __syncthreads();
  const int kx = t & 31;
#pragma unroll
  for (int i = 0; i < 4; ++i) {
    int qw = (t >> 5) + 8 * i;
    const unsigned short* qrow = qlds + qw * 64;
    const float* rhrow = rh + kx * 65;
    const float* rwrow = rw + (qw - kx + 31) * 65;
    float sh = 0.f, sw = 0.f;
    for (int d = 0; d < 64; ++d) {
      float qv = bf2f(qrow[d]);
      sh += qv * rhrow[d];
      sw += qv * rwrow[d];
    }
    size_t base = (((size_t)bh * 1024) + qh * 32 + qw) * 32 + kx;
    relh[base] = sh * 8.0f;   // undo q-prescale (x8) and land in log2e units
    relw[base] = sw * 8.0f;
  }
}

// ---------------------- flash attention v2 (swapped 32x32) -----------------
// grid (9 qtiles x 128, 96 bh), 4 waves x 32 q-rows. Lane owns q = base+l&31.
// S^T = mfma32(K, Q) -> lane holds 32 P-values (rows=keys in regs).
// O^T = mfma32(V^T, P^T) -> cols stay q -> lane-uniform rescale/normalize.
__global__ __launch_bounds__(256) void k_flash(
    const unsigned short* __restrict__ qbf, const unsigned short* __restrict__ kbf,
    const unsigned short* __restrict__ vtbf, const float* __restrict__ relh,
    const float* __restrict__ relw, unsigned short* __restrict__ attnbf) {
  __shared__ __align__(16) char smem[32768];
  unsigned short* lK = (unsigned short*)smem;            // [64 key][64 d] swz, 8KB
  unsigned short* lV = (unsigned short*)(smem + 8192);   // [64 d][64 key] swz, 8KB
  float* lrhT = (float*)(smem + 16384);                  // [32 kh][128 q], 16KB

  const int bh = blockIdx.y, qt = blockIdx.x, t = threadIdx.x;
  const int w = t >> 6, l = t & 63;
  const int lq = l & 31;          // q within wave tile; also MFMA row/col id
  const int hf = l >> 5;
  const int q_in_blk = w * 32 + lq;
  const int qglob = qt * 128 + q_in_blk;
  const bool hasbias = (qt < 8);
  const bool qvalid = (qglob < 1088);

  if (hasbias) {  // stage relh transposed: lrhT[kh][q]
    const float* src = relh + (((size_t)bh * 1024) + qt * 128 + (t >> 1)) * 32 + (t & 1) * 16;
    float4 a = *(const float4*)(src);
    float4 b = *(const float4*)(src + 4);
    float4 c = *(const float4*)(src + 8);
    float4 d = *(const float4*)(src + 12);
    float tmp[16] = {a.x, a.y, a.z, a.w, b.x, b.y, b.z, b.w,
                     c.x, c.y, c.z, c.w, d.x, d.y, d.z, d.w};
    int qq = t >> 1, khb = (t & 1) * 16;
#pragma unroll
    for (int j = 0; j < 16; ++j) lrhT[(khb + j) * 128 + qq] = tmp[j];
  }
  float rw[16];
#pragma unroll
  for (int i = 0; i < 16; ++i) rw[i] = 0.f;
  if (hasbias) {
    const float* rwp = relw + (((size_t)bh * 1024) + qglob) * 32;
#pragma unroll
    for (int i = 0; i < 16; ++i) {
      int kw = (i & 3) + 8 * (i >> 2) + 4 * hf;
      rw[i] = rwp[kw];
    }
  }
  bf16x8 qf[4];
  {
    const unsigned short* qp = qbf + (((size_t)bh * 1088) + qglob) * 64 + hf * 8;
#pragma unroll
    for (int d = 0; d < 4; ++d) qf[d] = *(const bf16x8*)(qp + d * 16);
  }

  f32x16 o0, o1;
#pragma unroll
  for (int i = 0; i < 16; ++i) { o0[i] = 0.f; o1[i] = 0.f; }
  float mrun = -1e30f, lrun = 0.f;
  const unsigned short* Kb = kbf + (size_t)bh * 1088 * 64;
  const unsigned short* Vb = vtbf + (size_t)bh * 64 * 1088;
  const int srow = t >> 3;
  const int scs = (t & 7) ^ (srow & 7);

  for (int kc = 0; kc < 17; ++kc) {
#pragma unroll
    for (int p = 0; p < 2; ++p) {
      int r = p * 32 + srow;
      gload_lds16(Kb + ((size_t)(kc * 64 + r)) * 64 + scs * 8, lK + p * 2048 + w * 512);
      gload_lds16(Vb + (size_t)r * 1088 + kc * 64 + scs * 8, lV + p * 2048 + w * 512);
    }
    __syncthreads();

    const bool tail = (kc == 16);
    float rh0 = 0.f, rh1 = 0.f;
    if (hasbias && !tail) {
      rh0 = lrhT[(kc * 2) * 128 + q_in_blk];
      rh1 = lrhT[(kc * 2 + 1) * 128 + q_in_blk];
    }
    f32x16 s0, s1;
#pragma unroll
    for (int i = 0; i < 16; ++i) { s0[i] = rh0; s1[i] = rh1; }
    const int row1 = 32 + lq;
#pragma unroll
    for (int db = 0; db < 4; ++db) {
      int sl = db * 2 + hf;
      bf16x8 k0 = *(const bf16x8*)(lK + lq * 64 + ((sl ^ (lq & 7)) << 3));
      s0 = __builtin_amdgcn_mfma_f32_32x32x16_bf16(k0, qf[db], s0, 0, 0, 0);
      if (!tail) {
        bf16x8 k1 = *(const bf16x8*)(lK + row1 * 64 + ((sl ^ (row1 & 7)) << 3));
        s1 = __builtin_amdgcn_mfma_f32_32x32x16_bf16(k1, qf[db], s1, 0, 0, 0);
      }
    }
    // biased scores (rw only; rh was folded into C-init; tail has no bias)
    float p[32];
#pragma unroll
    for (int i = 0; i < 16; ++i) p[i] = tail ? s0[i] : (s0[i] + rw[i]);
#pragma unroll
    for (int i = 0; i < 16; ++i) p[16 + i] = s1[i] + rw[i];
    // chunk max (tree)
    float mt[16];
    if (tail) {
#pragma unroll
      for (int i = 0; i < 8; ++i) mt[i] = fmaxf(p[i], p[8 + i]);
#pragma unroll
      for (int s = 4; s > 0; s >>= 1)
#pragma unroll
        for (int i = 0; i < s; ++i) mt[i] = fmaxf(mt[i], mt[i + s]);
    } else {
#pragma unroll
      for (int i = 0; i < 16; ++i) mt[i] = fmaxf(p[i], p[16 + i]);
#pragma unroll
      for (int s = 8; s > 0; s >>= 1)
#pragma unroll
        for (int i = 0; i < s; ++i) mt[i] = fmaxf(mt[i], mt[i + s]);
    }
    float mc = fmaxf(mt[0], __shfl_xor(mt[0], 32));
    if (!__all(mc - mrun <= 8.0f)) {  // T13 defer-max
      float mnew = fmaxf(mrun, mc);
      float al = exp2_hw(mrun - mnew);
      lrun *= al;
#pragma unroll
      for (int i = 0; i < 16; ++i) { o0[i] *= al; o1[i] *= al; }
      mrun = mnew;
    }
    const int nv = tail ? 16 : 32;
#pragma unroll 32
    for (int i = 0; i < 32; ++i) {
      if (i < nv) p[i] = exp2_hw(p[i] - mrun);
    }
    float st[16];
    if (tail) {
#pragma unroll
      for (int i = 0; i < 8; ++i) st[i] = p[i] + p[8 + i];
#pragma unroll
      for (int s = 4; s > 0; s >>= 1)
#pragma unroll
        for (int i = 0; i < s; ++i) st[i] += st[i + s];
    } else {
#pragma unroll
      for (int i = 0; i < 16; ++i) st[i] = p[i] + p[16 + i];
#pragma unroll
      for (int s = 8; s > 0; s >>= 1)
#pragma unroll
        for (int i = 0; i < s; ++i) st[i] += st[i + s];
    }
    lrun += st[0] + __shfl_xor(st[0], 32);
    // pack P -> B-frags (P^T) and PV: O^T += mfma(V^T, P^T)
#pragma unroll
    for (int kb = 0; kb < 4; ++kb) {
      if (tail && kb >= 2) break;
      unsigned X0 = cvtpk_bf16(p[kb * 8 + 0], p[kb * 8 + 1]);
      unsigned X1 = cvtpk_bf16(p[kb * 8 + 2], p[kb * 8 + 3]);
      unsigned Y0 = cvtpk_bf16(p[kb * 8 + 4], p[kb * 8 + 5]);
      unsigned Y1 = cvtpk_bf16(p[kb * 8 + 6], p[kb * 8 + 7]);
      i32x2 r0 = __builtin_amdgcn_permlane32_swap(X0, Y0, false, false);
      i32x2 r1 = __builtin_amdgcn_permlane32_swap(X1, Y1, false, false);
      i32x4 pd;
      pd.x = r0.x; pd.y = r1.x; pd.z = r0.y; pd.w = r1.y;
      bf16x8 pf = __builtin_bit_cast(bf16x8, pd);
      int sl = kb * 2 + hf;
      bf16x8 v0 = *(const bf16x8*)(lV + lq * 64 + ((sl ^ (lq & 7)) << 3));
      bf16x8 v1 = *(const bf16x8*)(lV + row1 * 64 + ((sl ^ (row1 & 7)) << 3));
      o0 = __builtin_amdgcn_mfma_f32_32x32x16_bf16(v0, pf, o0, 0, 0, 0);
      o1 = __builtin_amdgcn_mfma_f32_32x32x16_bf16(v1, pf, o1, 0, 0, 0);
    }
    __syncthreads();
  }

  // epilogue: normalize, transpose via per-wave swizzled LDS, coalesced store
  __syncthreads();
  float* tile = (float*)(smem + w * 8192);  // [64 d][32 q] f32, XOR-swizzled
  float inv = 1.f / lrun;
#pragma unroll
  for (int i = 0; i < 16; ++i) {
    int d0 = (i & 3) + 8 * (i >> 2) + 4 * hf;
    tile[d0 * 32 + (lq ^ (d0 & 31))] = o0[i] * inv;
    int d1 = 32 + d0;
    tile[d1 * 32 + (lq ^ (d1 & 31))] = o1[i] * inv;
  }
  __builtin_amdgcn_s_waitcnt(0);  // lgkmcnt(0): wave-local LDS RAW
  if (qvalid) {
    const int b = bh / 12, head = bh - (bh / 12) * 12;
    unsigned dw[16];
#pragma unroll
    for (int j = 0; j < 16; ++j) {
      int da = hf * 32 + 2 * j, dbi = da + 1;
      float v0 = tile[da * 32 + (lq ^ (da & 31))];
      float v1 = tile[dbi * 32 + (lq ^ (dbi & 31))];
      dw[j] = cvtpk_bf16(v0, v1);
    }
    unsigned short* dst = attnbf + (((size_t)b * 1088) + qglob) * 768 + head * 64 + hf * 32;
#pragma unroll
    for (int j = 0; j < 4; ++j) {
      uint4 u = make_uint4(dw[4 * j], dw[4 * j + 1], dw[4 * j + 2], dw[4 * j + 3]);
      *(uint4*)(dst + j * 8) = u;
    }
  }
}

// ---------------------------------------------------------------------------
extern "C" void kernel_launch(void* const* d_in, const int* in_sizes, int n_in,
                              void* d_out, int out_size, void* d_ws, size_t ws_size,
                              hipStream_t stream) {
  const float* x = (const float*)d_in[0];
  const float* qkv_w = (const float*)d_in[1];
  const float* qkv_b = (const float*)d_in[2];
  const float* proj_w = (const float*)d_in[3];
  const float* proj_b = (const float*)d_in[4];
  const float* rph = (const float*)d_in[5];
  const float* rpw = (const float*)d_in[6];
  float* out = (float*)d_out;

  char* ws = (char*)d_ws;
  unsigned short* xbf = (unsigned short*)(ws + 0);
  unsigned short* attnbf = xbf;  // alias: xbf dead after qkv GEMM
  unsigned short* wqkv = (unsigned short*)(ws + 13369344);
  unsigned short* wproj = (unsigned short*)(ws + 16908288);
  unsigned short* qbf = (unsigned short*)(ws + 18087936);
  unsigned short* kbf = (unsigned short*)(ws + 31457280);
  unsigned short* vbf = (unsigned short*)(ws + 44826624);
  unsigned short* vtbf = (unsigned short*)(ws + 58195968);
  float* relh = (float*)(ws + 71565312);
  float* relw = (float*)(ws + 84148224);

  k_cvt<<<dim3(1024), dim3(256), 0, stream>>>(x, xbf, 8704 * 768 / 4);
  k_cvt<<<dim3(512), dim3(256), 0, stream>>>(qkv_w, wqkv, 2304 * 768 / 4);
  k_cvt<<<dim3(128), dim3(256), 0, stream>>>(proj_w, wproj, 768 * 768 / 4);
  k_gemm_bt<0><<<dim3(68, 18), dim3(256), 0, stream>>>(xbf, wqkv, qkv_b, nullptr,
                                                       qbf, kbf, vbf, 8704, 2304, 768);
  k_vt<<<dim3(17, 96), dim3(256), 0, stream>>>(vbf, vtbf);
  k_relpos<<<dim3(32, 96), dim3(256), 0, stream>>>(qbf, rph, rpw, relh, relw);
  k_flash<<<dim3(9, 96), dim3(256), 0, stream>>>(qbf, kbf, vtbf, relh, relw, attnbf);
  k_gemm_bt<1><<<dim3(68, 6), dim3(256), 0, stream>>>(attnbf, wproj, proj_b, out,
                                                      nullptr, nullptr, nullptr, 8704, 768, 768);
}

// Round 3
// 232.022 us; speedup vs baseline: 1.3565x; 1.1239x over previous
//
#include <hip/hip_runtime.h>
#include <stdint.h>

// ---------------------------------------------------------------------------
// Attention_24206435680257 : SAM-style attention, B=8 N=1088 C=768 nh=12 hd=64
//   1. cvt x, qkv_w, proj_w -> bf16
//   2. GEMM qkv = x @ qkv_w^T + b -> scatter q,k,v [96][1088][64] bf16
//      (q pre-scaled by 0.125*log2e so flash softmax runs in exp2 domain)
//   3. transpose v -> vT [96][64][1088]
//   4. relpos: relh/relw [96][1024][32] fp32 (x8 to recover log2e*bias)
//   5. flash v3: swapped 32x32 MFMA, in-register softmax, K/V double-buffer
//      prefetch pipeline (T3-minimum: STAGE early, one vmcnt(0)+barrier/chunk)
//   6. GEMM out = attn @ proj_w^T + proj_b -> fp32 d_out
// ---------------------------------------------------------------------------

typedef __attribute__((ext_vector_type(8))) short bf16x8;
typedef __attribute__((ext_vector_type(4))) float f32x4;
typedef __attribute__((ext_vector_type(16))) float f32x16;
typedef __attribute__((ext_vector_type(2))) int i32x2;
typedef __attribute__((ext_vector_type(4))) int i32x4;

#define DEVINL static __device__ __forceinline__

DEVINL unsigned short f2bf(float f) {
  unsigned u = __builtin_bit_cast(unsigned, f);
  u += 0x7FFFu + ((u >> 16) & 1u);
  return (unsigned short)(u >> 16);
}
DEVINL float bf2f(unsigned short h) {
  unsigned u = ((unsigned)h) << 16;
  return __builtin_bit_cast(float, u);
}
DEVINL void gload_lds16(const void* g, void* l) {
  __builtin_amdgcn_global_load_lds(
      (const __attribute__((address_space(1))) unsigned int*)g,
      (__attribute__((address_space(3))) unsigned int*)l, 16, 0, 0);
}
DEVINL float exp2_hw(float x) {
  float r;
  asm("v_exp_f32 %0, %1" : "=v"(r) : "v"(x));
  return r;
}
DEVINL unsigned cvtpk_bf16(float lo, float hi) {
  unsigned r;
  asm("v_cvt_pk_bf16_f32 %0, %1, %2" : "=v"(r) : "v"(lo), "v"(hi));
  return r;
}

// ------------------------------- f32 -> bf16 -------------------------------
__global__ void k_cvt(const float* __restrict__ in, unsigned short* __restrict__ out, int n4) {
  int i = blockIdx.x * 256 + threadIdx.x;
  int stride = gridDim.x * 256;
  for (; i < n4; i += stride) {
    float4 v = ((const float4*)in)[i];
    ushort4 o = make_ushort4(f2bf(v.x), f2bf(v.y), f2bf(v.z), f2bf(v.w));
    ((ushort4*)out)[i] = o;
  }
}

// ------------------------- bt-GEMM: C = A @ Bm^T ---------------------------
template <int EPI>
__global__ __launch_bounds__(256) void k_gemm_bt(
    const unsigned short* __restrict__ A, const unsigned short* __restrict__ Bm,
    const float* __restrict__ bias, float* __restrict__ Cf,
    unsigned short* __restrict__ oq, unsigned short* __restrict__ ok,
    unsigned short* __restrict__ ov, int M, int N, int K) {
  __shared__ __align__(16) unsigned short lA[128 * 64];
  __shared__ __align__(16) unsigned short lB[128 * 64];
  const int t = threadIdx.x;
  const int w = t >> 6, l = t & 63;
  const int wm = w >> 1, wn = w & 1;
  const int g = l >> 4, li = l & 15;
  const int row0 = blockIdx.x * 128, col0 = blockIdx.y * 128;
  const unsigned short* Ab = A + (size_t)row0 * K;
  const unsigned short* Bb = Bm + (size_t)col0 * K;
  const f32x4 zero = {0.f, 0.f, 0.f, 0.f};
  f32x4 acc[4][4];
#pragma unroll
  for (int i = 0; i < 4; ++i)
#pragma unroll
    for (int j = 0; j < 4; ++j) acc[i][j] = zero;

  const int srow = t >> 3;
  const int scs = (t & 7) ^ (srow & 7);

  for (int kt = 0; kt < K; kt += 64) {
#pragma unroll
    for (int p = 0; p < 4; ++p) {
      int r = p * 32 + srow;
      gload_lds16(Ab + (size_t)r * K + kt + scs * 8, lA + p * 2048 + w * 512);
      gload_lds16(Bb + (size_t)r * K + kt + scs * 8, lB + p * 2048 + w * 512);
    }
    __syncthreads();
#pragma unroll
    for (int kh = 0; kh < 2; ++kh) {
      bf16x8 af[4], bfv[4];
#pragma unroll
      for (int mf = 0; mf < 4; ++mf) {
        int r = wm * 64 + mf * 16 + li;
        int c8 = (kh * 4 + g) ^ (r & 7);
        af[mf] = *(const bf16x8*)(lA + r * 64 + c8 * 8);
      }
#pragma unroll
      for (int nf = 0; nf < 4; ++nf) {
        int r = wn * 64 + nf * 16 + li;
        int c8 = (kh * 4 + g) ^ (r & 7);
        bfv[nf] = *(const bf16x8*)(lB + r * 64 + c8 * 8);
      }
#pragma unroll
      for (int mf = 0; mf < 4; ++mf)
#pragma unroll
        for (int nf = 0; nf < 4; ++nf)
          acc[mf][nf] = __builtin_amdgcn_mfma_f32_16x16x32_bf16(af[mf], bfv[nf], acc[mf][nf], 0, 0, 0);
    }
    __syncthreads();
  }

#pragma unroll
  for (int mf = 0; mf < 4; ++mf) {
#pragma unroll
    for (int nf = 0; nf < 4; ++nf) {
      const int jc = col0 + wn * 64 + nf * 16 + li;
      const float bj = bias[jc];
#pragma unroll
      for (int rg = 0; rg < 4; ++rg) {
        const int m = row0 + wm * 64 + mf * 16 + g * 4 + rg;
        float val = acc[mf][nf][rg] + bj;
        if (EPI == 0) {
          int which = jc / 768;
          int jr = jc - which * 768;
          int head = jr >> 6, d = jr & 63;
          int b = m / 1088;
          int n = m - b * 1088;
          size_t idx = (((size_t)(b * 12 + head)) * 1088 + n) * 64 + d;
          if (which == 0) val *= 0.18033688011112042f;  // 0.125 * log2(e)
          unsigned short bv = f2bf(val);
          if (which == 0) oq[idx] = bv;
          else if (which == 1) ok[idx] = bv;
          else ov[idx] = bv;
        } else {
          Cf[(size_t)m * N + jc] = val;
        }
      }
    }
  }
}

// ------------------------- v [96][1088][64] -> vT [96][64][1088] -----------
__global__ __launch_bounds__(256) void k_vt(const unsigned short* __restrict__ v,
                                            unsigned short* __restrict__ vt) {
  __shared__ unsigned short tile[64 * 66];
  const int bh = blockIdx.y, nt = blockIdx.x, t = threadIdx.x;
  const unsigned short* src = v + (((size_t)bh * 1088) + nt * 64) * 64;
#pragma unroll
  for (int i = 0; i < 2; ++i) {
    int c = t + 256 * i;
    int r = c >> 3, d8 = (c & 7) * 8;
    uint4 val = *(const uint4*)(src + (size_t)r * 64 + d8);
    const unsigned short* s8 = (const unsigned short*)&val;
#pragma unroll
    for (int j = 0; j < 8; ++j) tile[r * 66 + d8 + j] = s8[j];
  }
  __syncthreads();
  unsigned short* dst = vt + ((size_t)bh * 64) * 1088 + nt * 64;
#pragma unroll
  for (int i = 0; i < 2; ++i) {
    int c = t + 256 * i;
    int d = c >> 3, n8 = (c & 7) * 8;
    unsigned short tmp[8];
#pragma unroll
    for (int j = 0; j < 8; ++j) tmp[j] = tile[(n8 + j) * 66 + d];
    *(uint4*)(dst + (size_t)d * 1088 + n8) = *(const uint4*)tmp;
  }
}

// ---- relh[bh][q][kh] = 8 * sum_d qscaled[bh][q][d]*rel_pos_h[qh-kh+31][d] --
__global__ __launch_bounds__(256) void k_relpos(const unsigned short* __restrict__ qbf,
                                                const float* __restrict__ rph,
                                                const float* __restrict__ rpw,
                                                float* __restrict__ relh,
                                                float* __restrict__ relw) {
  __shared__ __align__(16) unsigned short qlds[32 * 64];
  __shared__ float rh[32 * 65];
  __shared__ float rw[63 * 65];
  const int bh = blockIdx.y, qh = blockIdx.x, t = threadIdx.x;
  {
    int qw = t >> 3, d8 = (t & 7) * 8;
    *(uint4*)(qlds + qw * 64 + d8) =
        *(const uint4*)(qbf + (((size_t)bh * 1088) + qh * 32 + qw) * 64 + d8);
  }
  for (int idx = t; idx < 32 * 64; idx += 256) {
    int r = idx >> 6, d = idx & 63;
    rh[r * 65 + d] = rph[(size_t)(qh + 31 - r) * 64 + d];
  }
  for (int idx = t; idx < 63 * 64; idx += 256) {
    int r = idx >> 6, d = idx & 63;
    rw[r * 65 + d] = rpw[(size_t)r * 64 + d];
  }
  __syncthreads();
  const int kx = t & 31;
#pragma unroll
  for (int i = 0; i < 4; ++i) {
    int qw = (t >> 5) + 8 * i;
    const unsigned short* qrow = qlds + qw * 64;
    const float* rhrow = rh + kx * 65;
    const float* rwrow = rw + (qw - kx + 31) * 65;
    float sh = 0.f, sw = 0.f;
    for (int d = 0; d < 64; ++d) {
      float qv = bf2f(qrow[d]);
      sh += qv * rhrow[d];
      sw += qv * rwrow[d];
    }
    size_t base = (((size_t)bh * 1024) + qh * 32 + qw) * 32 + kx;
    relh[base] = sh * 8.0f;   // undo q-prescale (x8) and land in log2e units
    relw[base] = sw * 8.0f;
  }
}

// ---------------- flash attention v3 (swapped 32x32 + prefetch) ------------
// grid (9 qtiles x 128, 96 bh), 4 waves x 32 q-rows. Lane owns q = base+l&31.
// S^T = mfma32(K, Q); O^T = mfma32(V^T, P^T). K/V double-buffered in LDS;
// chunk kc+1 staged at top of section kc; one vmcnt(0)+s_barrier per chunk.
__global__ __launch_bounds__(256) void k_flash(
    const unsigned short* __restrict__ qbf, const unsigned short* __restrict__ kbf,
    const unsigned short* __restrict__ vtbf, const float* __restrict__ relh,
    const float* __restrict__ relw, unsigned short* __restrict__ attnbf) {
  __shared__ __align__(16) char smem[49152];
  unsigned short* lK0 = (unsigned short*)smem;            // [64 key][64 d] swz
  unsigned short* lV0 = (unsigned short*)(smem + 8192);   // [64 d][64 key] swz
  unsigned short* lK1 = (unsigned short*)(smem + 16384);
  unsigned short* lV1 = (unsigned short*)(smem + 24576);
  float* lrhT = (float*)(smem + 32768);                   // [32 kh][128 q]

  const int bh = blockIdx.y, qt = blockIdx.x, t = threadIdx.x;
  const int w = t >> 6, l = t & 63;
  const int lq = l & 31;
  const int hf = l >> 5;
  const int q_in_blk = w * 32 + lq;
  const int qglob = qt * 128 + q_in_blk;
  const bool hasbias = (qt < 8);
  const bool qvalid = (qglob < 1088);
  const int row1 = 32 + lq;

  const unsigned short* Kb = kbf + (size_t)bh * 1088 * 64;
  const unsigned short* Vb = vtbf + (size_t)bh * 64 * 1088;
  const int srow = t >> 3;
  const int scs = (t & 7) ^ (srow & 7);

  auto stage = [&](int kc, unsigned short* dK, unsigned short* dV) {
#pragma unroll
    for (int p = 0; p < 2; ++p) {
      int r = p * 32 + srow;
      gload_lds16(Kb + ((size_t)(kc * 64 + r)) * 64 + scs * 8, dK + p * 2048 + w * 512);
      gload_lds16(Vb + (size_t)r * 1088 + kc * 64 + scs * 8, dV + p * 2048 + w * 512);
    }
  };

  stage(0, lK0, lV0);  // prologue prefetch

  if (hasbias) {  // stage relh transposed: lrhT[kh][q]
    const float* src = relh + (((size_t)bh * 1024) + qt * 128 + (t >> 1)) * 32 + (t & 1) * 16;
    float4 a = *(const float4*)(src);
    float4 b = *(const float4*)(src + 4);
    float4 c = *(const float4*)(src + 8);
    float4 d = *(const float4*)(src + 12);
    float tmp[16] = {a.x, a.y, a.z, a.w, b.x, b.y, b.z, b.w,
                     c.x, c.y, c.z, c.w, d.x, d.y, d.z, d.w};
    int qq = t >> 1, khb = (t & 1) * 16;
#pragma unroll
    for (int j = 0; j < 16; ++j) lrhT[(khb + j) * 128 + qq] = tmp[j];
  }
  float rw[16];
#pragma unroll
  for (int i = 0; i < 16; ++i) rw[i] = 0.f;
  if (hasbias) {
    const float* rwp = relw + (((size_t)bh * 1024) + qglob) * 32;
#pragma unroll
    for (int i = 0; i < 16; ++i) {
      int kw = (i & 3) + 8 * (i >> 2) + 4 * hf;
      rw[i] = rwp[kw];
    }
  }
  bf16x8 qf[4];
  {
    const unsigned short* qp = qbf + (((size_t)bh * 1088) + qglob) * 64 + hf * 8;
#pragma unroll
    for (int d = 0; d < 4; ++d) qf[d] = *(const bf16x8*)(qp + d * 16);
  }

  f32x16 o0, o1;
#pragma unroll
  for (int i = 0; i < 16; ++i) { o0[i] = 0.f; o1[i] = 0.f; }
  float mrun = -1e30f, lrun = 0.f;

  asm volatile("s_waitcnt vmcnt(0) lgkmcnt(0)" ::: "memory");
  __builtin_amdgcn_s_barrier();

  auto body = [&](int kc, unsigned short* cK, unsigned short* cV,
                  unsigned short* nK, unsigned short* nV) {
    stage(kc + 1, nK, nV);  // prefetch next chunk; flies under compute below
    float rh0 = 0.f, rh1 = 0.f;
    if (hasbias) {
      rh0 = lrhT[(kc * 2) * 128 + q_in_blk];
      rh1 = lrhT[(kc * 2 + 1) * 128 + q_in_blk];
    }
    f32x16 s0, s1;
#pragma unroll
    for (int i = 0; i < 16; ++i) { s0[i] = rh0; s1[i] = rh1; }
    __builtin_amdgcn_s_setprio(1);
#pragma unroll
    for (int db = 0; db < 4; ++db) {
      int sl = db * 2 + hf;
      bf16x8 k0 = *(const bf16x8*)(cK + lq * 64 + ((sl ^ (lq & 7)) << 3));
      bf16x8 k1 = *(const bf16x8*)(cK + row1 * 64 + ((sl ^ (row1 & 7)) << 3));
      s0 = __builtin_amdgcn_mfma_f32_32x32x16_bf16(k0, qf[db], s0, 0, 0, 0);
      s1 = __builtin_amdgcn_mfma_f32_32x32x16_bf16(k1, qf[db], s1, 0, 0, 0);
    }
    __builtin_amdgcn_s_setprio(0);
    float p[32];
#pragma unroll
    for (int i = 0; i < 16; ++i) p[i] = s0[i] + rw[i];
#pragma unroll
    for (int i = 0; i < 16; ++i) p[16 + i] = s1[i] + rw[i];
    float mt[16];
#pragma unroll
    for (int i = 0; i < 16; ++i) mt[i] = fmaxf(p[i], p[16 + i]);
#pragma unroll
    for (int s = 8; s > 0; s >>= 1)
#pragma unroll
      for (int i = 0; i < s; ++i) mt[i] = fmaxf(mt[i], mt[i + s]);
    float mc = fmaxf(mt[0], __shfl_xor(mt[0], 32));
    if (!__all(mc - mrun <= 8.0f)) {  // T13 defer-max
      float mnew = fmaxf(mrun, mc);
      float al = exp2_hw(mrun - mnew);
      lrun *= al;
#pragma unroll
      for (int i = 0; i < 16; ++i) { o0[i] *= al; o1[i] *= al; }
      mrun = mnew;
    }
#pragma unroll
    for (int i = 0; i < 32; ++i) p[i] = exp2_hw(p[i] - mrun);
    float st[16];
#pragma unroll
    for (int i = 0; i < 16; ++i) st[i] = p[i] + p[16 + i];
#pragma unroll
    for (int s = 8; s > 0; s >>= 1)
#pragma unroll
      for (int i = 0; i < s; ++i) st[i] += st[i + s];
    lrun += st[0] + __shfl_xor(st[0], 32);
#pragma unroll
    for (int kb = 0; kb < 4; ++kb) {
      unsigned X0 = cvtpk_bf16(p[kb * 8 + 0], p[kb * 8 + 1]);
      unsigned X1 = cvtpk_bf16(p[kb * 8 + 2], p[kb * 8 + 3]);
      unsigned Y0 = cvtpk_bf16(p[kb * 8 + 4], p[kb * 8 + 5]);
      unsigned Y1 = cvtpk_bf16(p[kb * 8 + 6], p[kb * 8 + 7]);
      i32x2 r0 = __builtin_amdgcn_permlane32_swap(X0, Y0, false, false);
      i32x2 r1 = __builtin_amdgcn_permlane32_swap(X1, Y1, false, false);
      i32x4 pd;
      pd.x = r0.x; pd.y = r1.x; pd.z = r0.y; pd.w = r1.y;
      bf16x8 pf = __builtin_bit_cast(bf16x8, pd);
      int sl = kb * 2 + hf;
      bf16x8 v0 = *(const bf16x8*)(cV + lq * 64 + ((sl ^ (lq & 7)) << 3));
      bf16x8 v1 = *(const bf16x8*)(cV + row1 * 64 + ((sl ^ (row1 & 7)) << 3));
      __builtin_amdgcn_s_setprio(1);
      o0 = __builtin_amdgcn_mfma_f32_32x32x16_bf16(v0, pf, o0, 0, 0, 0);
      o1 = __builtin_amdgcn_mfma_f32_32x32x16_bf16(v1, pf, o1, 0, 0, 0);
      __builtin_amdgcn_s_setprio(0);
    }
    asm volatile("s_waitcnt vmcnt(0)" ::: "memory");  // prefetch landed
    __builtin_amdgcn_s_barrier();
  };

  for (int it = 0; it < 8; ++it) {
    body(2 * it, lK0, lV0, lK1, lV1);
    body(2 * it + 1, lK1, lV1, lK0, lV0);
  }

  {  // tail: keys 1024..1055 (rows 0..31 of chunk 16; 1056+ masked == absent)
    f32x16 s0;
#pragma unroll
    for (int i = 0; i < 16; ++i) s0[i] = 0.f;
    __builtin_amdgcn_s_setprio(1);
#pragma unroll
    for (int db = 0; db < 4; ++db) {
      int sl = db * 2 + hf;
      bf16x8 k0 = *(const bf16x8*)(lK0 + lq * 64 + ((sl ^ (lq & 7)) << 3));
      s0 = __builtin_amdgcn_mfma_f32_32x32x16_bf16(k0, qf[db], s0, 0, 0, 0);
    }
    __builtin_amdgcn_s_setprio(0);
    float p[16];
#pragma unroll
    for (int i = 0; i < 16; ++i) p[i] = s0[i];
    float mt[8];
#pragma unroll
    for (int i = 0; i < 8; ++i) mt[i] = fmaxf(p[i], p[8 + i]);
#pragma unroll
    for (int s = 4; s > 0; s >>= 1)
#pragma unroll
      for (int i = 0; i < s; ++i) mt[i] = fmaxf(mt[i], mt[i + s]);
    float mc = fmaxf(mt[0], __shfl_xor(mt[0], 32));
    if (!__all(mc - mrun <= 8.0f)) {
      float mnew = fmaxf(mrun, mc);
      float al = exp2_hw(mrun - mnew);
      lrun *= al;
#pragma unroll
      for (int i = 0; i < 16; ++i) { o0[i] *= al; o1[i] *= al; }
      mrun = mnew;
    }
#pragma unroll
    for (int i = 0; i < 16; ++i) p[i] = exp2_hw(p[i] - mrun);
    float st[8];
#pragma unroll
    for (int i = 0; i < 8; ++i) st[i] = p[i] + p[8 + i];
#pragma unroll
    for (int s = 4; s > 0; s >>= 1)
#pragma unroll
      for (int i = 0; i < s; ++i) st[i] += st[i + s];
    lrun += st[0] + __shfl_xor(st[0], 32);
#pragma unroll
    for (int kb = 0; kb < 2; ++kb) {
      unsigned X0 = cvtpk_bf16(p[kb * 8 + 0], p[kb * 8 + 1]);
      unsigned X1 = cvtpk_bf16(p[kb * 8 + 2], p[kb * 8 + 3]);
      unsigned Y0 = cvtpk_bf16(p[kb * 8 + 4], p[kb * 8 + 5]);
      unsigned Y1 = cvtpk_bf16(p[kb * 8 + 6], p[kb * 8 + 7]);
      i32x2 r0 = __builtin_amdgcn_permlane32_swap(X0, Y0, false, false);
      i32x2 r1 = __builtin_amdgcn_permlane32_swap(X1, Y1, false, false);
      i32x4 pd;
      pd.x = r0.x; pd.y = r1.x; pd.z = r0.y; pd.w = r1.y;
      bf16x8 pf = __builtin_bit_cast(bf16x8, pd);
      int sl = kb * 2 + hf;
      bf16x8 v0 = *(const bf16x8*)(lV0 + lq * 64 + ((sl ^ (lq & 7)) << 3));
      bf16x8 v1 = *(const bf16x8*)(lV0 + row1 * 64 + ((sl ^ (row1 & 7)) << 3));
      __builtin_amdgcn_s_setprio(1);
      o0 = __builtin_amdgcn_mfma_f32_32x32x16_bf16(v0, pf, o0, 0, 0, 0);
      o1 = __builtin_amdgcn_mfma_f32_32x32x16_bf16(v1, pf, o1, 0, 0, 0);
      __builtin_amdgcn_s_setprio(0);
    }
    __builtin_amdgcn_s_barrier();  // all reads of shared bufs done before reuse
  }

  // epilogue: normalize, transpose via per-wave swizzled LDS, coalesced store
  float* tile = (float*)(smem + w * 8192);  // [64 d][32 q] f32, XOR-swizzled
  float inv = 1.f / lrun;
#pragma unroll
  for (int i = 0; i < 16; ++i) {
    int d0 = (i & 3) + 8 * (i >> 2) + 4 * hf;
    tile[d0 * 32 + (lq ^ (d0 & 31))] = o0[i] * inv;
    int d1 = 32 + d0;
    tile[d1 * 32 + (lq ^ (d1 & 31))] = o1[i] * inv;
  }
  asm volatile("s_waitcnt lgkmcnt(0)" ::: "memory");  // wave-local LDS RAW
  if (qvalid) {
    const int b = bh / 12, head = bh - (bh / 12) * 12;
    unsigned dw[16];
#pragma unroll
    for (int j = 0; j < 16; ++j) {
      int da = hf * 32 + 2 * j, dbi = da + 1;
      float v0 = tile[da * 32 + (lq ^ (da & 31))];
      float v1 = tile[dbi * 32 + (lq ^ (dbi & 31))];
      dw[j] = cvtpk_bf16(v0, v1);
    }
    unsigned short* dst = attnbf + (((size_t)b * 1088) + qglob) * 768 + head * 64 + hf * 32;
#pragma unroll
    for (int j = 0; j < 4; ++j) {
      uint4 u = make_uint4(dw[4 * j], dw[4 * j + 1], dw[4 * j + 2], dw[4 * j + 3]);
      *(uint4*)(dst + j * 8) = u;
    }
  }
}

// ---------------------------------------------------------------------------
extern "C" void kernel_launch(void* const* d_in, const int* in_sizes, int n_in,
                              void* d_out, int out_size, void* d_ws, size_t ws_size,
                              hipStream_t stream) {
  const float* x = (const float*)d_in[0];
  const float* qkv_w = (const float*)d_in[1];
  const float* qkv_b = (const float*)d_in[2];
  const float* proj_w = (const float*)d_in[3];
  const float* proj_b = (const float*)d_in[4];
  const float* rph = (const float*)d_in[5];
  const float* rpw = (const float*)d_in[6];
  float* out = (float*)d_out;

  char* ws = (char*)d_ws;
  unsigned short* xbf = (unsigned short*)(ws + 0);
  unsigned short* attnbf = xbf;  // alias: xbf dead after qkv GEMM
  unsigned short* wqkv = (unsigned short*)(ws + 13369344);
  unsigned short* wproj = (unsigned short*)(ws + 16908288);
  unsigned short* qbf = (unsigned short*)(ws + 18087936);
  unsigned short* kbf = (unsigned short*)(ws + 31457280);
  unsigned short* vbf = (unsigned short*)(ws + 44826624);
  unsigned short* vtbf = (unsigned short*)(ws + 58195968);
  float* relh = (float*)(ws + 71565312);
  float* relw = (float*)(ws + 84148224);

  k_cvt<<<dim3(1024), dim3(256), 0, stream>>>(x, xbf, 8704 * 768 / 4);
  k_cvt<<<dim3(512), dim3(256), 0, stream>>>(qkv_w, wqkv, 2304 * 768 / 4);
  k_cvt<<<dim3(128), dim3(256), 0, stream>>>(proj_w, wproj, 768 * 768 / 4);
  k_gemm_bt<0><<<dim3(68, 18), dim3(256), 0, stream>>>(xbf, wqkv, qkv_b, nullptr,
                                                       qbf, kbf, vbf, 8704, 2304, 768);
  k_vt<<<dim3(17, 96), dim3(256), 0, stream>>>(vbf, vtbf);
  k_relpos<<<dim3(32, 96), dim3(256), 0, stream>>>(qbf, rph, rpw, relh, relw);
  k_flash<<<dim3(9, 96), dim3(256), 0, stream>>>(qbf, kbf, vtbf, relh, relw, attnbf);
  k_gemm_bt<1><<<dim3(68, 6), dim3(256), 0, stream>>>(attnbf, wproj, proj_b, out,
                                                      nullptr, nullptr, nullptr, 8704, 768, 768);
}

// Round 4
// 172.523 us; speedup vs baseline: 1.8244x; 1.3449x over previous
//
#include <hip/hip_runtime.h>
#include <stdint.h>

// ---------------------------------------------------------------------------
// Attention_24206435680257 : SAM-style attention, B=8 N=1088 C=768 nh=12 hd=64
//   1. cvt x, qkv_w, proj_w -> bf16
//   2. GEMM qkv = x @ qkv_w^T + b -> scatter q,k,v [96][1088][64] bf16
//      (q pre-scaled by 0.125*log2e so flash softmax runs in exp2 domain)
//   3. transpose v -> vT [96][64][1088]; then cvt rph/rpw -> bf16 (vbf dead)
//   4. relpos via MFMA: relh[q,kh]=(Q_h rph^T)[w,h+31-kh] direct;
//      relw[q,kw]=(Q_h rpw^T)[w,w+31-kw] via G_w in LDS + diagonal gather
//   5. flash v3: swapped 32x32 MFMA, in-register softmax, K/V double-buffer
//      prefetch pipeline (STAGE early, one vmcnt(0)+barrier per chunk)
//   6. GEMM out = attn @ proj_w^T + proj_b -> fp32 d_out
// ---------------------------------------------------------------------------

typedef __attribute__((ext_vector_type(8))) short bf16x8;
typedef __attribute__((ext_vector_type(4))) float f32x4;
typedef __attribute__((ext_vector_type(16))) float f32x16;
typedef __attribute__((ext_vector_type(2))) int i32x2;
typedef __attribute__((ext_vector_type(4))) int i32x4;

#define DEVINL static __device__ __forceinline__

DEVINL unsigned short f2bf(float f) {
  unsigned u = __builtin_bit_cast(unsigned, f);
  u += 0x7FFFu + ((u >> 16) & 1u);
  return (unsigned short)(u >> 16);
}
DEVINL float bf2f(unsigned short h) {
  unsigned u = ((unsigned)h) << 16;
  return __builtin_bit_cast(float, u);
}
DEVINL void gload_lds16(const void* g, void* l) {
  __builtin_amdgcn_global_load_lds(
      (const __attribute__((address_space(1))) unsigned int*)g,
      (__attribute__((address_space(3))) unsigned int*)l, 16, 0, 0);
}
DEVINL float exp2_hw(float x) {
  float r;
  asm("v_exp_f32 %0, %1" : "=v"(r) : "v"(x));
  return r;
}
DEVINL unsigned cvtpk_bf16(float lo, float hi) {
  unsigned r;
  asm("v_cvt_pk_bf16_f32 %0, %1, %2" : "=v"(r) : "v"(lo), "v"(hi));
  return r;
}

// ------------------------------- f32 -> bf16 -------------------------------
__global__ void k_cvt(const float* __restrict__ in, unsigned short* __restrict__ out, int n4) {
  int i = blockIdx.x * 256 + threadIdx.x;
  int stride = gridDim.x * 256;
  for (; i < n4; i += stride) {
    float4 v = ((const float4*)in)[i];
    ushort4 o = make_ushort4(f2bf(v.x), f2bf(v.y), f2bf(v.z), f2bf(v.w));
    ((ushort4*)out)[i] = o;
  }
}

// ------------------------- bt-GEMM: C = A @ Bm^T ---------------------------
template <int EPI>
__global__ __launch_bounds__(256) void k_gemm_bt(
    const unsigned short* __restrict__ A, const unsigned short* __restrict__ Bm,
    const float* __restrict__ bias, float* __restrict__ Cf,
    unsigned short* __restrict__ oq, unsigned short* __restrict__ ok,
    unsigned short* __restrict__ ov, int M, int N, int K) {
  __shared__ __align__(16) unsigned short lA[128 * 64];
  __shared__ __align__(16) unsigned short lB[128 * 64];
  const int t = threadIdx.x;
  const int w = t >> 6, l = t & 63;
  const int wm = w >> 1, wn = w & 1;
  const int g = l >> 4, li = l & 15;
  const int row0 = blockIdx.x * 128, col0 = blockIdx.y * 128;
  const unsigned short* Ab = A + (size_t)row0 * K;
  const unsigned short* Bb = Bm + (size_t)col0 * K;
  const f32x4 zero = {0.f, 0.f, 0.f, 0.f};
  f32x4 acc[4][4];
#pragma unroll
  for (int i = 0; i < 4; ++i)
#pragma unroll
    for (int j = 0; j < 4; ++j) acc[i][j] = zero;

  const int srow = t >> 3;
  const int scs = (t & 7) ^ (srow & 7);

  for (int kt = 0; kt < K; kt += 64) {
#pragma unroll
    for (int p = 0; p < 4; ++p) {
      int r = p * 32 + srow;
      gload_lds16(Ab + (size_t)r * K + kt + scs * 8, lA + p * 2048 + w * 512);
      gload_lds16(Bb + (size_t)r * K + kt + scs * 8, lB + p * 2048 + w * 512);
    }
    __syncthreads();
#pragma unroll
    for (int kh = 0; kh < 2; ++kh) {
      bf16x8 af[4], bfv[4];
#pragma unroll
      for (int mf = 0; mf < 4; ++mf) {
        int r = wm * 64 + mf * 16 + li;
        int c8 = (kh * 4 + g) ^ (r & 7);
        af[mf] = *(const bf16x8*)(lA + r * 64 + c8 * 8);
      }
#pragma unroll
      for (int nf = 0; nf < 4; ++nf) {
        int r = wn * 64 + nf * 16 + li;
        int c8 = (kh * 4 + g) ^ (r & 7);
        bfv[nf] = *(const bf16x8*)(lB + r * 64 + c8 * 8);
      }
#pragma unroll
      for (int mf = 0; mf < 4; ++mf)
#pragma unroll
        for (int nf = 0; nf < 4; ++nf)
          acc[mf][nf] = __builtin_amdgcn_mfma_f32_16x16x32_bf16(af[mf], bfv[nf], acc[mf][nf], 0, 0, 0);
    }
    __syncthreads();
  }

#pragma unroll
  for (int mf = 0; mf < 4; ++mf) {
#pragma unroll
    for (int nf = 0; nf < 4; ++nf) {
      const int jc = col0 + wn * 64 + nf * 16 + li;
      const float bj = bias[jc];
#pragma unroll
      for (int rg = 0; rg < 4; ++rg) {
        const int m = row0 + wm * 64 + mf * 16 + g * 4 + rg;
        float val = acc[mf][nf][rg] + bj;
        if (EPI == 0) {
          int which = jc / 768;
          int jr = jc - which * 768;
          int head = jr >> 6, d = jr & 63;
          int b = m / 1088;
          int n = m - b * 1088;
          size_t idx = (((size_t)(b * 12 + head)) * 1088 + n) * 64 + d;
          if (which == 0) val *= 0.18033688011112042f;  // 0.125 * log2(e)
          unsigned short bv = f2bf(val);
          if (which == 0) oq[idx] = bv;
          else if (which == 1) ok[idx] = bv;
          else ov[idx] = bv;
        } else {
          Cf[(size_t)m * N + jc] = val;
        }
      }
    }
  }
}

// ------------------------- v [96][1088][64] -> vT [96][64][1088] -----------
__global__ __launch_bounds__(256) void k_vt(const unsigned short* __restrict__ v,
                                            unsigned short* __restrict__ vt) {
  __shared__ unsigned short tile[64 * 66];
  const int bh = blockIdx.y, nt = blockIdx.x, t = threadIdx.x;
  const unsigned short* src = v + (((size_t)bh * 1088) + nt * 64) * 64;
#pragma unroll
  for (int i = 0; i < 2; ++i) {
    int c = t + 256 * i;
    int r = c >> 3, d8 = (c & 7) * 8;
    uint4 val = *(const uint4*)(src + (size_t)r * 64 + d8);
    const unsigned short* s8 = (const unsigned short*)&val;
#pragma unroll
    for (int j = 0; j < 8; ++j) tile[r * 66 + d8 + j] = s8[j];
  }
  __syncthreads();
  unsigned short* dst = vt + ((size_t)bh * 64) * 1088 + nt * 64;
#pragma unroll
  for (int i = 0; i < 2; ++i) {
    int c = t + 256 * i;
    int d = c >> 3, n8 = (c & 7) * 8;
    unsigned short tmp[8];
#pragma unroll
    for (int j = 0; j < 8; ++j) tmp[j] = tile[(n8 + j) * 66 + d];
    *(uint4*)(dst + (size_t)d * 1088 + n8) = *(const uint4*)tmp;
  }
}

// --------------------------- relpos via MFMA -------------------------------
// grid (8, 96), 4 waves; wave wv handles h = blockIdx.x*4 + wv.
// relh[h*32+w][kh] = (Q_h rph^T)[w][h+31-kh]  -> direct MFMA, B rows reversed
// relw[h*32+w][kw] = (Q_h rpw^T)[w][w+31-kw]  -> G_w to LDS, diagonal gather
// Output scaled x8: undoes q prescale (0.125*log2e) -> log2e * raw bias.
__global__ __launch_bounds__(256) void k_relpos(const unsigned short* __restrict__ qbf,
                                                const unsigned short* __restrict__ rphbf,
                                                const unsigned short* __restrict__ rpwbf,
                                                float* __restrict__ relh,
                                                float* __restrict__ relw) {
  __shared__ float gw[4][32 * 64];  // per-wave G_w scratch (8 KB each)
  const int bh = blockIdx.y, t = threadIdx.x;
  const int wv = t >> 6, l = t & 63;
  const int h = blockIdx.x * 4 + wv;
  const int lk = l & 31, hf = l >> 5;

  bf16x8 qf[4];  // A-frag: Q row = h*32 + lk
  {
    const unsigned short* qp = qbf + (((size_t)bh * 1088) + h * 32 + lk) * 64 + hf * 8;
#pragma unroll
    for (int db = 0; db < 4; ++db) qf[db] = *(const bf16x8*)(qp + db * 16);
  }

  f32x16 dh, g0, g1;
#pragma unroll
  for (int i = 0; i < 16; ++i) { dh[i] = 0.f; g0[i] = 0.f; g1[i] = 0.f; }

  {  // relh: B rows = rph[h+31-kh], kh = lane
    const unsigned short* bp = rphbf + (size_t)(h + 31 - lk) * 64 + hf * 8;
#pragma unroll
    for (int db = 0; db < 4; ++db) {
      bf16x8 bfr = *(const bf16x8*)(bp + db * 16);
      dh = __builtin_amdgcn_mfma_f32_32x32x16_bf16(qf[db], bfr, dh, 0, 0, 0);
    }
  }
  {  // G_w tile 0: j = lane (0..31); tile 1: j = 32+lane (row 63 unused garbage)
    const unsigned short* bp0 = rpwbf + (size_t)lk * 64 + hf * 8;
    const unsigned short* bp1 = rpwbf + (size_t)(32 + lk) * 64 + hf * 8;
#pragma unroll
    for (int db = 0; db < 4; ++db) {
      bf16x8 b0 = *(const bf16x8*)(bp0 + db * 16);
      bf16x8 b1 = *(const bf16x8*)(bp1 + db * 16);
      g0 = __builtin_amdgcn_mfma_f32_32x32x16_bf16(qf[db], b0, g0, 0, 0, 0);
      g1 = __builtin_amdgcn_mfma_f32_32x32x16_bf16(qf[db], b1, g1, 0, 0, 0);
    }
  }
  // park G_w in per-wave LDS: G[w][j]   (writes: consecutive lanes -> consec)
  float* G = gw[wv];
#pragma unroll
  for (int i = 0; i < 16; ++i) {
    int row = (i & 3) + 8 * (i >> 2) + 4 * hf;
    G[row * 64 + lk] = g0[i];
    G[row * 64 + 32 + lk] = g1[i];
  }
  // diagonal gather (wave-local; compiler inserts lgkmcnt):
  // relw[w][kw=lane] = G[w][w+31-lane] -> addr = w*65 + 31 - lane (conflict-free)
  f32x16 dwv;
#pragma unroll
  for (int i = 0; i < 16; ++i) {
    int row = (i & 3) + 8 * (i >> 2) + 4 * hf;
    dwv[i] = G[row * 65 + 31 - lk];
  }
  // stores: per reg, lanes cover two contiguous 128B runs
  float* outh = relh + (((size_t)bh * 1024) + h * 32) * 32;
  float* outw = relw + (((size_t)bh * 1024) + h * 32) * 32;
#pragma unroll
  for (int i = 0; i < 16; ++i) {
    int row = (i & 3) + 8 * (i >> 2) + 4 * hf;
    outh[row * 32 + lk] = dh[i] * 8.0f;
    outw[row * 32 + lk] = dwv[i] * 8.0f;
  }
}

// ---------------- flash attention v3 (swapped 32x32 + prefetch) ------------
// grid (9 qtiles x 128, 96 bh), 4 waves x 32 q-rows. Lane owns q = base+l&31.
// S^T = mfma32(K, Q); O^T = mfma32(V^T, P^T). K/V double-buffered in LDS;
// chunk kc+1 staged at top of section kc; one vmcnt(0)+s_barrier per chunk.
__global__ __launch_bounds__(256) void k_flash(
    const unsigned short* __restrict__ qbf, const unsigned short* __restrict__ kbf,
    const unsigned short* __restrict__ vtbf, const float* __restrict__ relh,
    const float* __restrict__ relw, unsigned short* __restrict__ attnbf) {
  __shared__ __align__(16) char smem[49152];
  unsigned short* lK0 = (unsigned short*)smem;            // [64 key][64 d] swz
  unsigned short* lV0 = (unsigned short*)(smem + 8192);   // [64 d][64 key] swz
  unsigned short* lK1 = (unsigned short*)(smem + 16384);
  unsigned short* lV1 = (unsigned short*)(smem + 24576);
  float* lrhT = (float*)(smem + 32768);                   // [32 kh][128 q]

  const int bh = blockIdx.y, qt = blockIdx.x, t = threadIdx.x;
  const int w = t >> 6, l = t & 63;
  const int lq = l & 31;
  const int hf = l >> 5;
  const int q_in_blk = w * 32 + lq;
  const int qglob = qt * 128 + q_in_blk;
  const bool hasbias = (qt < 8);
  const bool qvalid = (qglob < 1088);
  const int row1 = 32 + lq;

  const unsigned short* Kb = kbf + (size_t)bh * 1088 * 64;
  const unsigned short* Vb = vtbf + (size_t)bh * 64 * 1088;
  const int srow = t >> 3;
  const int scs = (t & 7) ^ (srow & 7);

  auto stage = [&](int kc, unsigned short* dK, unsigned short* dV) {
#pragma unroll
    for (int p = 0; p < 2; ++p) {
      int r = p * 32 + srow;
      gload_lds16(Kb + ((size_t)(kc * 64 + r)) * 64 + scs * 8, dK + p * 2048 + w * 512);
      gload_lds16(Vb + (size_t)r * 1088 + kc * 64 + scs * 8, dV + p * 2048 + w * 512);
    }
  };

  stage(0, lK0, lV0);  // prologue prefetch

  if (hasbias) {  // stage relh transposed: lrhT[kh][q]
    const float* src = relh + (((size_t)bh * 1024) + qt * 128 + (t >> 1)) * 32 + (t & 1) * 16;
    float4 a = *(const float4*)(src);
    float4 b = *(const float4*)(src + 4);
    float4 c = *(const float4*)(src + 8);
    float4 d = *(const float4*)(src + 12);
    float tmp[16] = {a.x, a.y, a.z, a.w, b.x, b.y, b.z, b.w,
                     c.x, c.y, c.z, c.w, d.x, d.y, d.z, d.w};
    int qq = t >> 1, khb = (t & 1) * 16;
#pragma unroll
    for (int j = 0; j < 16; ++j) lrhT[(khb + j) * 128 + qq] = tmp[j];
  }
  float rw[16];
#pragma unroll
  for (int i = 0; i < 16; ++i) rw[i] = 0.f;
  if (hasbias) {
    const float* rwp = relw + (((size_t)bh * 1024) + qglob) * 32;
#pragma unroll
    for (int i = 0; i < 16; ++i) {
      int kw = (i & 3) + 8 * (i >> 2) + 4 * hf;
      rw[i] = rwp[kw];
    }
  }
  bf16x8 qf[4];
  {
    const unsigned short* qp = qbf + (((size_t)bh * 1088) + qglob) * 64 + hf * 8;
#pragma unroll
    for (int d = 0; d < 4; ++d) qf[d] = *(const bf16x8*)(qp + d * 16);
  }

  f32x16 o0, o1;
#pragma unroll
  for (int i = 0; i < 16; ++i) { o0[i] = 0.f; o1[i] = 0.f; }
  float mrun = -1e30f, lrun = 0.f;

  asm volatile("s_waitcnt vmcnt(0) lgkmcnt(0)" ::: "memory");
  __builtin_amdgcn_s_barrier();

  auto body = [&](int kc, unsigned short* cK, unsigned short* cV,
                  unsigned short* nK, unsigned short* nV) {
    stage(kc + 1, nK, nV);  // prefetch next chunk; flies under compute below
    float rh0 = 0.f, rh1 = 0.f;
    if (hasbias) {
      rh0 = lrhT[(kc * 2) * 128 + q_in_blk];
      rh1 = lrhT[(kc * 2 + 1) * 128 + q_in_blk];
    }
    f32x16 s0, s1;
#pragma unroll
    for (int i = 0; i < 16; ++i) { s0[i] = rh0; s1[i] = rh1; }
    __builtin_amdgcn_s_setprio(1);
#pragma unroll
    for (int db = 0; db < 4; ++db) {
      int sl = db * 2 + hf;
      bf16x8 k0 = *(const bf16x8*)(cK + lq * 64 + ((sl ^ (lq & 7)) << 3));
      bf16x8 k1 = *(const bf16x8*)(cK + row1 * 64 + ((sl ^ (row1 & 7)) << 3));
      s0 = __builtin_amdgcn_mfma_f32_32x32x16_bf16(k0, qf[db], s0, 0, 0, 0);
      s1 = __builtin_amdgcn_mfma_f32_32x32x16_bf16(k1, qf[db], s1, 0, 0, 0);
    }
    __builtin_amdgcn_s_setprio(0);
    float p[32];
#pragma unroll
    for (int i = 0; i < 16; ++i) p[i] = s0[i] + rw[i];
#pragma unroll
    for (int i = 0; i < 16; ++i) p[16 + i] = s1[i] + rw[i];
    float mt[16];
#pragma unroll
    for (int i = 0; i < 16; ++i) mt[i] = fmaxf(p[i], p[16 + i]);
#pragma unroll
    for (int s = 8; s > 0; s >>= 1)
#pragma unroll
      for (int i = 0; i < s; ++i) mt[i] = fmaxf(mt[i], mt[i + s]);
    float mc = fmaxf(mt[0], __shfl_xor(mt[0], 32));
    if (!__all(mc - mrun <= 8.0f)) {  // T13 defer-max
      float mnew = fmaxf(mrun, mc);
      float al = exp2_hw(mrun - mnew);
      lrun *= al;
#pragma unroll
      for (int i = 0; i < 16; ++i) { o0[i] *= al; o1[i] *= al; }
      mrun = mnew;
    }
#pragma unroll
    for (int i = 0; i < 32; ++i) p[i] = exp2_hw(p[i] - mrun);
    float st[16];
#pragma unroll
    for (int i = 0; i < 16; ++i) st[i] = p[i] + p[16 + i];
#pragma unroll
    for (int s = 8; s > 0; s >>= 1)
#pragma unroll
      for (int i = 0; i < s; ++i) st[i] += st[i + s];
    lrun += st[0] + __shfl_xor(st[0], 32);
#pragma unroll
    for (int kb = 0; kb < 4; ++kb) {
      unsigned X0 = cvtpk_bf16(p[kb * 8 + 0], p[kb * 8 + 1]);
      unsigned X1 = cvtpk_bf16(p[kb * 8 + 2], p[kb * 8 + 3]);
      unsigned Y0 = cvtpk_bf16(p[kb * 8 + 4], p[kb * 8 + 5]);
      unsigned Y1 = cvtpk_bf16(p[kb * 8 + 6], p[kb * 8 + 7]);
      i32x2 r0 = __builtin_amdgcn_permlane32_swap(X0, Y0, false, false);
      i32x2 r1 = __builtin_amdgcn_permlane32_swap(X1, Y1, false, false);
      i32x4 pd;
      pd.x = r0.x; pd.y = r1.x; pd.z = r0.y; pd.w = r1.y;
      bf16x8 pf = __builtin_bit_cast(bf16x8, pd);
      int sl = kb * 2 + hf;
      bf16x8 v0 = *(const bf16x8*)(cV + lq * 64 + ((sl ^ (lq & 7)) << 3));
      bf16x8 v1 = *(const bf16x8*)(cV + row1 * 64 + ((sl ^ (row1 & 7)) << 3));
      __builtin_amdgcn_s_setprio(1);
      o0 = __builtin_amdgcn_mfma_f32_32x32x16_bf16(v0, pf, o0, 0, 0, 0);
      o1 = __builtin_amdgcn_mfma_f32_32x32x16_bf16(v1, pf, o1, 0, 0, 0);
      __builtin_amdgcn_s_setprio(0);
    }
    asm volatile("s_waitcnt vmcnt(0)" ::: "memory");  // prefetch landed
    __builtin_amdgcn_s_barrier();
  };

  for (int it = 0; it < 8; ++it) {
    body(2 * it, lK0, lV0, lK1, lV1);
    body(2 * it + 1, lK1, lV1, lK0, lV0);
  }

  {  // tail: keys 1024..1055 (rows 0..31 of chunk 16; 1056+ masked == absent)
    f32x16 s0;
#pragma unroll
    for (int i = 0; i < 16; ++i) s0[i] = 0.f;
    __builtin_amdgcn_s_setprio(1);
#pragma unroll
    for (int db = 0; db < 4; ++db) {
      int sl = db * 2 + hf;
      bf16x8 k0 = *(const bf16x8*)(lK0 + lq * 64 + ((sl ^ (lq & 7)) << 3));
      s0 = __builtin_amdgcn_mfma_f32_32x32x16_bf16(k0, qf[db], s0, 0, 0, 0);
    }
    __builtin_amdgcn_s_setprio(0);
    float p[16];
#pragma unroll
    for (int i = 0; i < 16; ++i) p[i] = s0[i];
    float mt[8];
#pragma unroll
    for (int i = 0; i < 8; ++i) mt[i] = fmaxf(p[i], p[8 + i]);
#pragma unroll
    for (int s = 4; s > 0; s >>= 1)
#pragma unroll
      for (int i = 0; i < s; ++i) mt[i] = fmaxf(mt[i], mt[i + s]);
    float mc = fmaxf(mt[0], __shfl_xor(mt[0], 32));
    if (!__all(mc - mrun <= 8.0f)) {
      float mnew = fmaxf(mrun, mc);
      float al = exp2_hw(mrun - mnew);
      lrun *= al;
#pragma unroll
      for (int i = 0; i < 16; ++i) { o0[i] *= al; o1[i] *= al; }
      mrun = mnew;
    }
#pragma unroll
    for (int i = 0; i < 16; ++i) p[i] = exp2_hw(p[i] - mrun);
    float st[8];
#pragma unroll
    for (int i = 0; i < 8; ++i) st[i] = p[i] + p[8 + i];
#pragma unroll
    for (int s = 4; s > 0; s >>= 1)
#pragma unroll
      for (int i = 0; i < s; ++i) st[i] += st[i + s];
    lrun += st[0] + __shfl_xor(st[0], 32);
#pragma unroll
    for (int kb = 0; kb < 2; ++kb) {
      unsigned X0 = cvtpk_bf16(p[kb * 8 + 0], p[kb * 8 + 1]);
      unsigned X1 = cvtpk_bf16(p[kb * 8 + 2], p[kb * 8 + 3]);
      unsigned Y0 = cvtpk_bf16(p[kb * 8 + 4], p[kb * 8 + 5]);
      unsigned Y1 = cvtpk_bf16(p[kb * 8 + 6], p[kb * 8 + 7]);
      i32x2 r0 = __builtin_amdgcn_permlane32_swap(X0, Y0, false, false);
      i32x2 r1 = __builtin_amdgcn_permlane32_swap(X1, Y1, false, false);
      i32x4 pd;
      pd.x = r0.x; pd.y = r1.x; pd.z = r0.y; pd.w = r1.y;
      bf16x8 pf = __builtin_bit_cast(bf16x8, pd);
      int sl = kb * 2 + hf;
      bf16x8 v0 = *(const bf16x8*)(lV0 + lq * 64 + ((sl ^ (lq & 7)) << 3));
      bf16x8 v1 = *(const bf16x8*)(lV0 + row1 * 64 + ((sl ^ (row1 & 7)) << 3));
      __builtin_amdgcn_s_setprio(1);
      o0 = __builtin_amdgcn_mfma_f32_32x32x16_bf16(v0, pf, o0, 0, 0, 0);
      o1 = __builtin_amdgcn_mfma_f32_32x32x16_bf16(v1, pf, o1, 0, 0, 0);
      __builtin_amdgcn_s_setprio(0);
    }
    __builtin_amdgcn_s_barrier();  // all reads of shared bufs done before reuse
  }

  // epilogue: normalize, transpose via per-wave swizzled LDS, coalesced store
  float* tile = (float*)(smem + w * 8192);  // [64 d][32 q] f32, XOR-swizzled
  float inv = 1.f / lrun;
#pragma unroll
  for (int i = 0; i < 16; ++i) {
    int d0 = (i & 3) + 8 * (i >> 2) + 4 * hf;
    tile[d0 * 32 + (lq ^ (d0 & 31))] = o0[i] * inv;
    int d1 = 32 + d0;
    tile[d1 * 32 + (lq ^ (d1 & 31))] = o1[i] * inv;
  }
  asm volatile("s_waitcnt lgkmcnt(0)" ::: "memory");  // wave-local LDS RAW
  if (qvalid) {
    const int b = bh / 12, head = bh - (bh / 12) * 12;
    unsigned dw[16];
#pragma unroll
    for (int j = 0; j < 16; ++j) {
      int da = hf * 32 + 2 * j, dbi = da + 1;
      float v0 = tile[da * 32 + (lq ^ (da & 31))];
      float v1 = tile[dbi * 32 + (lq ^ (dbi & 31))];
      dw[j] = cvtpk_bf16(v0, v1);
    }
    unsigned short* dst = attnbf + (((size_t)b * 1088) + qglob) * 768 + head * 64 + hf * 32;
#pragma unroll
    for (int j = 0; j < 4; ++j) {
      uint4 u = make_uint4(dw[4 * j], dw[4 * j + 1], dw[4 * j + 2], dw[4 * j + 3]);
      *(uint4*)(dst + j * 8) = u;
    }
  }
}

// ---------------------------------------------------------------------------
extern "C" void kernel_launch(void* const* d_in, const int* in_sizes, int n_in,
                              void* d_out, int out_size, void* d_ws, size_t ws_size,
                              hipStream_t stream) {
  const float* x = (const float*)d_in[0];
  const float* qkv_w = (const float*)d_in[1];
  const float* qkv_b = (const float*)d_in[2];
  const float* proj_w = (const float*)d_in[3];
  const float* proj_b = (const float*)d_in[4];
  const float* rph = (const float*)d_in[5];
  const float* rpw = (const float*)d_in[6];
  float* out = (float*)d_out;

  char* ws = (char*)d_ws;
  unsigned short* xbf = (unsigned short*)(ws + 0);
  unsigned short* attnbf = xbf;  // alias: xbf dead after qkv GEMM
  unsigned short* wqkv = (unsigned short*)(ws + 13369344);
  unsigned short* wproj = (unsigned short*)(ws + 16908288);
  unsigned short* qbf = (unsigned short*)(ws + 18087936);
  unsigned short* kbf = (unsigned short*)(ws + 31457280);
  unsigned short* vbf = (unsigned short*)(ws + 44826624);
  unsigned short* vtbf = (unsigned short*)(ws + 58195968);
  float* relh = (float*)(ws + 71565312);
  float* relw = (float*)(ws + 84148224);
  // rph/rpw bf16 tables live in the vbf region (dead after k_vt)
  unsigned short* rphbf = (unsigned short*)(ws + 44826624);
  unsigned short* rpwbf = (unsigned short*)(ws + 44826624 + 8192);

  k_cvt<<<dim3(1024), dim3(256), 0, stream>>>(x, xbf, 8704 * 768 / 4);
  k_cvt<<<dim3(512), dim3(256), 0, stream>>>(qkv_w, wqkv, 2304 * 768 / 4);
  k_cvt<<<dim3(128), dim3(256), 0, stream>>>(proj_w, wproj, 768 * 768 / 4);
  k_gemm_bt<0><<<dim3(68, 18), dim3(256), 0, stream>>>(xbf, wqkv, qkv_b, nullptr,
                                                       qbf, kbf, vbf, 8704, 2304, 768);
  k_vt<<<dim3(17, 96), dim3(256), 0, stream>>>(vbf, vtbf);
  k_cvt<<<dim3(4, 1), dim3(256), 0, stream>>>(rph, rphbf, 63 * 64 / 4);
  k_cvt<<<dim3(4, 1), dim3(256), 0, stream>>>(rpw, rpwbf, 63 * 64 / 4);
  k_relpos<<<dim3(8, 96), dim3(256), 0, stream>>>(qbf, rphbf, rpwbf, relh, relw);
  k_flash<<<dim3(9, 96), dim3(256), 0, stream>>>(qbf, kbf, vtbf, relh, relw, attnbf);
  k_gemm_bt<1><<<dim3(68, 6), dim3(256), 0, stream>>>(attnbf, wproj, proj_b, out,
                                                      nullptr, nullptr, nullptr, 8704, 768, 768);
}